// Round 1
// baseline (26.508 us; speedup 1.0000x reference)
//
#include <hip/hip_runtime.h>

#define NBLADE 8
#define DDIM 256

__global__ __launch_bounds__(256) void geoprod_kernel(
    const float* __restrict__ x, const float* __restrict__ w,
    float* __restrict__ out, int n_threads)
{
    __shared__ float tab[64];
    const int tid = threadIdx.x;
    if (tid < 64) {
        const int order[8] = {0, 1, 2, 4, 3, 5, 6, 7};
        const int i = tid >> 3, j = tid & 7;
        const int a = order[i], b = order[j];
        int s = 0, t = a >> 1;
        while (t) { s += __popc(t & b); t >>= 1; }
        const float wij = w[tid];                 // w[i][j], row-major
        const float sig = 1.0f / (1.0f + expf(-wij));
        tab[tid] = (s & 1) ? -sig : sig;          // sign(i,j) * sigmoid(w[i,j])
    }
    __syncthreads();

    const int gid = blockIdx.x * 256 + tid;
    if (gid >= n_threads) return;

    // thread handles (b,t) = gid>>6, d-quad = (gid&63)*4
    const int base = (gid >> 6) * (NBLADE * DDIM) + (gid & 63) * 4;

    float4 xv[8];
    #pragma unroll
    for (int i = 0; i < 8; ++i)
        xv[i] = *reinterpret_cast<const float4*>(x + base + i * DDIM);

    float4 acc[8];
    #pragma unroll
    for (int k = 0; k < 8; ++k) acc[k] = make_float4(0.f, 0.f, 0.f, 0.f);

    // kmap[i][j] = idx[mask[i] ^ mask[j]] — compile-time so acc[] stays in registers
    static constexpr int kmap[8][8] = {
        {0,1,2,3,4,5,6,7},
        {1,0,4,5,2,3,7,6},
        {2,4,0,6,1,7,3,5},
        {3,5,6,0,7,1,2,4},
        {4,2,1,7,0,6,5,3},
        {5,3,7,1,6,0,4,2},
        {6,7,3,2,5,4,0,1},
        {7,6,5,4,3,2,1,0},
    };

    // diagonal: mask^mask = 0 -> k = 0 for all i
    #pragma unroll
    for (int i = 0; i < 8; ++i) {
        const float c = tab[i * 8 + i];
        acc[0].x += c * xv[i].x * xv[i].x;
        acc[0].y += c * xv[i].y * xv[i].y;
        acc[0].z += c * xv[i].z * xv[i].z;
        acc[0].w += c * xv[i].w * xv[i].w;
    }

    // off-diagonal: (i,j) and (j,i) hit the same k — fold coefficients
    #pragma unroll
    for (int i = 0; i < 8; ++i) {
        #pragma unroll
        for (int j = i + 1; j < 8; ++j) {
            const float c = tab[i * 8 + j] + tab[j * 8 + i];
            const int k = kmap[i][j];
            acc[k].x += c * xv[i].x * xv[j].x;
            acc[k].y += c * xv[i].y * xv[j].y;
            acc[k].z += c * xv[i].z * xv[j].z;
            acc[k].w += c * xv[i].w * xv[j].w;
        }
    }

    #pragma unroll
    for (int k = 0; k < 8; ++k)
        *reinterpret_cast<float4*>(out + base + k * DDIM) = acc[k];
}

extern "C" void kernel_launch(void* const* d_in, const int* in_sizes, int n_in,
                              void* d_out, int out_size, void* d_ws, size_t ws_size,
                              hipStream_t stream) {
    const float* x = (const float*)d_in[0];
    const float* w = (const float*)d_in[1];
    float* out = (float*)d_out;

    const int total = in_sizes[0];            // B*T*NB*D elements
    const int n_threads = total / 32;         // each thread: 8 blades x 4 elems
    const int blocks = (n_threads + 255) / 256;

    geoprod_kernel<<<blocks, 256, 0, stream>>>(x, w, out, n_threads);
}

// Round 2
// 25.860 us; speedup vs baseline: 1.0250x; 1.0250x over previous
//
#include <hip/hip_runtime.h>

#define NBLADE 8
#define DDIM 256

__global__ __launch_bounds__(256) void geoprod_kernel(
    const float* __restrict__ x, const float* __restrict__ w,
    float* __restrict__ out, int n_threads)
{
    // ctab layout: [0..7] diagonal coeffs (all -> k=0), [8..43] folded upper-tri coeffs
    __shared__ float ctab[44];
    const int tid = threadIdx.x;
    if (tid < 64) {
        const int order[8] = {0, 1, 2, 4, 3, 5, 6, 7};
        const int i = tid >> 3, j = tid & 7;
        const int a = order[i], b = order[j];
        int s = 0, t = a >> 1;
        while (t) { s += __popc(t & b); t >>= 1; }
        const float sig = 1.0f / (1.0f + expf(-w[tid]));
        const float v = (s & 1) ? -sig : sig;     // sign(i,j) * sigmoid(w[i,j])
        if (i == j) {
            ctab[i] = v;                          // diagonal
        } else if (i < j) {
            // folded slot for pair (i,j), i<j: 8 + (#pairs before row i) + (j-i-1)
            const int slot = 8 + (i * (15 - i)) / 2 + (j - i - 1);
            atomicAdd(&ctab[slot], 0.0f);         // no-op placeholder removed below
        }
    }
    // Need ctab[slot] = v(i,j) + v(j,i). Do it in two phases without atomics:
    // phase 1: i<j threads write v; phase 2: i>j threads add their v.
    __syncthreads();
    if (tid < 64) {
        const int order[8] = {0, 1, 2, 4, 3, 5, 6, 7};
        const int i = tid >> 3, j = tid & 7;
        if (i < j) {
            const int a = order[i], b = order[j];
            int s = 0, t = a >> 1;
            while (t) { s += __popc(t & b); t >>= 1; }
            const float sig = 1.0f / (1.0f + expf(-w[i * 8 + j]));
            float v = (s & 1) ? -sig : sig;
            // partner (j,i)
            int s2 = 0, t2 = b >> 1;
            while (t2) { s2 += __popc(t2 & a); t2 >>= 1; }
            const float sig2 = 1.0f / (1.0f + expf(-w[j * 8 + i]));
            v += (s2 & 1) ? -sig2 : sig2;
            const int slot = 8 + (i * (15 - i)) / 2 + (j - i - 1);
            ctab[slot] = v;
        }
    }
    __syncthreads();

    const int gid = blockIdx.x * 256 + tid;
    if (gid >= n_threads) return;

    const int base = (gid >> 6) * (NBLADE * DDIM) + (gid & 63) * 4;

    float4 xv[8];
    #pragma unroll
    for (int i = 0; i < 8; ++i)
        xv[i] = *reinterpret_cast<const float4*>(x + base + i * DDIM);

    float4 acc[8];
    #pragma unroll
    for (int k = 0; k < 8; ++k) acc[k] = make_float4(0.f, 0.f, 0.f, 0.f);

    static constexpr int kmap[8][8] = {
        {0,1,2,3,4,5,6,7},
        {1,0,4,5,2,3,7,6},
        {2,4,0,6,1,7,3,5},
        {3,5,6,0,7,1,2,4},
        {4,2,1,7,0,6,5,3},
        {5,3,7,1,6,0,4,2},
        {6,7,3,2,5,4,0,1},
        {7,6,5,4,3,2,1,0},
    };

    // diagonal terms: all land in k=0
    #pragma unroll
    for (int i = 0; i < 8; ++i) {
        const float c = ctab[i];
        acc[0].x += c * xv[i].x * xv[i].x;
        acc[0].y += c * xv[i].y * xv[i].y;
        acc[0].z += c * xv[i].z * xv[i].z;
        acc[0].w += c * xv[i].w * xv[i].w;
    }

    // folded off-diagonal terms
    #pragma unroll
    for (int i = 0; i < 8; ++i) {
        #pragma unroll
        for (int j = i + 1; j < 8; ++j) {
            const int slot = 8 + (i * (15 - i)) / 2 + (j - i - 1);
            const float c = ctab[slot];
            const int k = kmap[i][j];
            acc[k].x += c * xv[i].x * xv[j].x;
            acc[k].y += c * xv[i].y * xv[j].y;
            acc[k].z += c * xv[i].z * xv[j].z;
            acc[k].w += c * xv[i].w * xv[j].w;
        }
    }

    // Non-temporal stores: out is write-once streaming data; keep it from
    // evicting x in L2/L3.
    #pragma unroll
    for (int k = 0; k < 8; ++k) {
        float* p = out + base + k * DDIM;
        __builtin_nontemporal_store(acc[k].x, p + 0);
        __builtin_nontemporal_store(acc[k].y, p + 1);
        __builtin_nontemporal_store(acc[k].z, p + 2);
        __builtin_nontemporal_store(acc[k].w, p + 3);
    }
}

extern "C" void kernel_launch(void* const* d_in, const int* in_sizes, int n_in,
                              void* d_out, int out_size, void* d_ws, size_t ws_size,
                              hipStream_t stream) {
    const float* x = (const float*)d_in[0];
    const float* w = (const float*)d_in[1];
    float* out = (float*)d_out;

    const int total = in_sizes[0];            // B*T*NB*D elements
    const int n_threads = total / 32;         // each thread: 8 blades x 4 elems
    const int blocks = (n_threads + 255) / 256;

    geoprod_kernel<<<blocks, 256, 0, stream>>>(x, w, out, n_threads);
}

// Round 3
// 25.487 us; speedup vs baseline: 1.0400x; 1.0146x over previous
//
#include <hip/hip_runtime.h>

#define DDIM 256

__global__ __launch_bounds__(256) void geoprod_kernel(
    const float* __restrict__ x, const float* __restrict__ w,
    float* __restrict__ out, int n_threads)
{
    // Folded coefficient table: [0..7] diagonal (all -> k=0),
    // [8..35] upper-tri pair coeffs c(i,j)+c(j,i).
    __shared__ __align__(16) float ctab[36];
    const int tid = threadIdx.x;
    if (tid < 64) {
        const int order[8] = {0, 1, 2, 4, 3, 5, 6, 7};
        const int i = tid >> 3, j = tid & 7;
        const int a = order[i], b = order[j];
        int s = 0, t = a >> 1;
        while (t) { s += __popc(t & b); t >>= 1; }
        const float sig = 1.0f / (1.0f + expf(-w[tid]));
        const float v = (s & 1) ? -sig : sig;      // sign(i,j)*sigmoid(w[i,j])
        const float vp = __shfl(v, j * 8 + i);     // partner term (j,i)
        if (i == j)      ctab[i] = v;
        else if (i < j)  ctab[8 + (i * (15 - i)) / 2 + (j - i - 1)] = v + vp;
    }
    __syncthreads();

    const int gid = blockIdx.x * 256 + tid;
    if (gid >= n_threads) return;

    // Bulk LDS -> VGPR copy; every later index is compile-time so c[] stays
    // in registers (no per-term ds_read in the FMA chain).
    float c[36];
    #pragma unroll
    for (int q = 0; q < 9; ++q)
        *reinterpret_cast<float4*>(&c[4 * q]) =
            *reinterpret_cast<const float4*>(&ctab[4 * q]);

    const int base = (gid >> 6) * (8 * DDIM) + (gid & 63) * 4;

    float4 xv[8];
    #pragma unroll
    for (int i = 0; i < 8; ++i)
        xv[i] = *reinterpret_cast<const float4*>(x + base + i * DDIM);

    // k = 0: only the 8 diagonal terms land here. Store immediately.
    {
        float4 a0 = make_float4(0.f, 0.f, 0.f, 0.f);
        #pragma unroll
        for (int i = 0; i < 8; ++i) {
            a0.x += c[i] * xv[i].x * xv[i].x;
            a0.y += c[i] * xv[i].y * xv[i].y;
            a0.z += c[i] * xv[i].z * xv[i].z;
            a0.w += c[i] * xv[i].w * xv[i].w;
        }
        float* p = out + base;
        __builtin_nontemporal_store(a0.x, p + 0);
        __builtin_nontemporal_store(a0.y, p + 1);
        __builtin_nontemporal_store(a0.z, p + 2);
        __builtin_nontemporal_store(a0.w, p + 3);
    }

    // k = 1..7: exactly 4 folded pairs each (Latin-square structure of the
    // Cayley map). Store each output quad as soon as it's complete so the
    // 8 NT stores interleave with compute instead of clustering at the tail.
    static constexpr int P[7][4][2] = {
        {{0,1},{2,4},{3,5},{6,7}},   // k=1
        {{0,2},{1,4},{3,6},{5,7}},   // k=2
        {{0,3},{1,5},{2,6},{4,7}},   // k=3
        {{0,4},{1,2},{3,7},{5,6}},   // k=4
        {{0,5},{1,3},{2,7},{4,6}},   // k=5
        {{0,6},{1,7},{2,3},{4,5}},   // k=6
        {{0,7},{1,6},{2,5},{3,4}},   // k=7
    };
    #pragma unroll
    for (int kk = 0; kk < 7; ++kk) {
        float4 a = make_float4(0.f, 0.f, 0.f, 0.f);
        #pragma unroll
        for (int t2 = 0; t2 < 4; ++t2) {
            const int i = P[kk][t2][0], j = P[kk][t2][1];
            const float cc = c[8 + (i * (15 - i)) / 2 + (j - i - 1)];
            a.x += cc * xv[i].x * xv[j].x;
            a.y += cc * xv[i].y * xv[j].y;
            a.z += cc * xv[i].z * xv[j].z;
            a.w += cc * xv[i].w * xv[j].w;
        }
        float* p = out + base + (kk + 1) * DDIM;
        __builtin_nontemporal_store(a.x, p + 0);
        __builtin_nontemporal_store(a.y, p + 1);
        __builtin_nontemporal_store(a.z, p + 2);
        __builtin_nontemporal_store(a.w, p + 3);
    }
}

extern "C" void kernel_launch(void* const* d_in, const int* in_sizes, int n_in,
                              void* d_out, int out_size, void* d_ws, size_t ws_size,
                              hipStream_t stream) {
    const float* x = (const float*)d_in[0];
    const float* w = (const float*)d_in[1];
    float* out = (float*)d_out;

    const int total = in_sizes[0];            // B*T*NB*D elements
    const int n_threads = total / 32;         // each thread: 8 blades x 4 elems
    const int blocks = (n_threads + 255) / 256;

    geoprod_kernel<<<blocks, 256, 0, stream>>>(x, w, out, n_threads);
}